// Round 5
// baseline (86.474 us; speedup 1.0000x reference)
//
#include <hip/hip_runtime.h>
#include <stdint.h>

// Problem constants (fixed by reference setup_inputs)
#define B_      8
#define N_      48
#define M_      (N_ * N_)       // 2304 candidate vectors per batch
#define CPB     128             // chunks (blocks) per batch
#define NBLK    (B_ * CPB)      // 1024 blocks = exactly 4 per CU, one round
#define TPB     256
#define PADSZ   2880            // compacted-table capacity incl zero padding
                                // (max index = K-1+3*CPB < 2304+384+128 = 2816)

// ws layout
#define WS_PARTS_OFF   0                          // float partS[NBLK]
#define WS_PARTC_OFF   (NBLK * sizeof(float))     // uint  partC[NBLK]
#define WS_TICKET_OFF  (2 * NBLK * sizeof(float)) // uint  ticket

// Single fused kernel.
// Key insight: a zero vector (sm thresholded to 0, or i==j) yields d = +/-0
// against EVERY partner -> contributes exactly 0 to both S and the nonzero
// count. Compacting to the K nonzero vectors (K ~ 1150 of 2304 at thr=0.5)
// is therefore EXACT for cnt and order-only for S: ~4x work cut.
// Rows are round-robin (chunk + q*CPB) for load balance at any K; the
// compacted table is zero-padded so out-of-range rows/columns contribute
// exactly 0 -> branch-free inner loop.
// Registers: 4 rows per pass, plain __launch_bounds__ — R2/R3 proved any
// occupancy attribute makes the allocator spill (14-46 MB scratch traffic).
__global__ __launch_bounds__(TPB) void fused_kernel(
    const float* __restrict__ gt,    // [B, 48, 2]
    const float* __restrict__ sm,    // [B, 48, 48]
    const float* __restrict__ thrp,  // [1]
    float* __restrict__ partS,
    unsigned int* __restrict__ partC,
    unsigned int* __restrict__ ticket,
    float* __restrict__ out)
{
    __shared__ float2 cxy[PADSZ];    // compacted (vx,vy): 23040 B, 2-way bank aliasing = free
    __shared__ float  cw [PADSZ];    // compacted 1/norm : 11520 B
    __shared__ float  gx[N_], gy[N_];
    __shared__ float  redS[4];
    __shared__ unsigned int redC[4];
    __shared__ int blockK;
    __shared__ int amLast;

    const int tid   = threadIdx.x;
    const int lane  = tid & 63;
    const int wave  = tid >> 6;
    const int b     = blockIdx.x >> 7;        // / CPB
    const int chunk = blockIdx.x & (CPB - 1); // % CPB

    if (tid == 0) blockK = 0;
    if (tid < N_) {
        float2 g = ((const float2*)gt)[b * N_ + tid];
        gx[tid] = g.x;
        gy[tid] = g.y;
    }
    __syncthreads();

    const float thr = thrp[0];
    // Build + compact. Exact IEEE single ops match numpy's (gt_i-gt_j)*sm.
    for (int idx = tid; idx < M_; idx += TPB) {   // 9 full iterations (2304 = 9*256)
        float s = sm[b * M_ + idx];
        s = (s < thr) ? 0.0f : s;
        int i = idx / N_;
        int j = idx - i * N_;
        float vx = __fmul_rn(__fsub_rn(gx[i], gx[j]), s);
        float vy = __fmul_rn(__fsub_rn(gy[i], gy[j]), s);
        bool keep = (vx != 0.0f) || (vy != 0.0f);   // exact-zero vectors drop out exactly
        unsigned long long mask = __ballot(keep);
        int base = 0;
        if (lane == 0 && mask) base = atomicAdd(&blockK, __popcll(mask));
        base = __shfl(base, 0, 64);
        if (keep) {
            int off = base + __popcll(mask & ((1ull << lane) - 1ull));
            cxy[off] = make_float2(vx, vy);
            cw [off] = rsqrtf(fmaf(vx, vx, fmaf(vy, vy, 2e-9f)));
        }
    }
    __syncthreads();
    const int K = blockK;
    // zero the pad: padded rows/columns contribute exactly 0 to S and cnt
    for (int i = K + tid; i < PADSZ; i += TPB) {
        cxy[i] = make_float2(0.0f, 0.0f);
        cw[i]  = 0.0f;
    }
    __syncthreads();

    const int KP = (K + 255) >> 8;   // column sweep iterations (~5)
    float total = 0.0f;
    unsigned int cnt = 0;

    // Row passes: 4 round-robin rows at a time (live set ~25 VGPRs).
    for (int r0 = chunk; r0 < K; r0 += 4 * CPB) {
        float rx0, ry0, rx1, ry1, rx2, ry2, rx3, ry3;
        {
            float2 t0 = cxy[r0];               // wave-uniform broadcast (free)
            float2 t1 = cxy[r0 + CPB];
            float2 t2 = cxy[r0 + 2 * CPB];
            float2 t3 = cxy[r0 + 3 * CPB];     // rows >= K read zeros -> exact no-op
            rx0 = t0.x; ry0 = t0.y; rx1 = t1.x; ry1 = t1.y;
            rx2 = t2.x; ry2 = t2.y; rx3 = t3.x; ry3 = t3.y;
        }
        float a0 = 0.0f, a1 = 0.0f, a2 = 0.0f, a3 = 0.0f;
        for (int k = 0; k < KP; ++k) {
            const int n = tid + (k << 8);
            const float2 c = cxy[n];           // ds_read_b64, reused x4 rows
            const float  w = cw[n];            // ds_read_b32
            // discrete mul/mul/add (no fma contraction): exact-zero count
            // semantics identical to the fp32 numpy reference
            float d0 = __fadd_rn(__fmul_rn(rx0, c.x), __fmul_rn(ry0, c.y));
            float d1 = __fadd_rn(__fmul_rn(rx1, c.x), __fmul_rn(ry1, c.y));
            float d2 = __fadd_rn(__fmul_rn(rx2, c.x), __fmul_rn(ry2, c.y));
            float d3 = __fadd_rn(__fmul_rn(rx3, c.x), __fmul_rn(ry3, c.y));
            cnt += (d0 != 0.0f) ? 1u : 0u;
            cnt += (d1 != 0.0f) ? 1u : 0u;
            cnt += (d2 != 0.0f) ? 1u : 0u;
            cnt += (d3 != 0.0f) ? 1u : 0u;
            a0 = fmaf(fabsf(d0), w, a0);       // |d| folds into VOP3 abs modifier
            a1 = fmaf(fabsf(d1), w, a1);
            a2 = fmaf(fabsf(d2), w, a2);
            a3 = fmaf(fabsf(d3), w, a3);
        }
        total = fmaf(a0, cw[r0],           total);  // hoisted row-norm factor
        total = fmaf(a1, cw[r0 + CPB],     total);
        total = fmaf(a2, cw[r0 + 2 * CPB], total);
        total = fmaf(a3, cw[r0 + 3 * CPB], total);  // pad rows: a=0 -> exact no-op
    }

    // wave64 shuffle reduce, then cross-wave via LDS
    for (int off = 32; off > 0; off >>= 1) {
        total += __shfl_down(total, off, 64);
        cnt   += __shfl_down(cnt,   off, 64);
    }
    if (lane == 0) { redS[wave] = total; redC[wave] = cnt; }
    __syncthreads();
    if (tid == 0) {
        partS[blockIdx.x] = redS[0] + redS[1] + redS[2] + redS[3];
        partC[blockIdx.x] = redC[0] + redC[1] + redC[2] + redC[3];
        __threadfence();                       // release partials device-wide
        unsigned int t = atomicAdd(ticket, 1u);
        amLast = (t == NBLK - 1) ? 1 : 0;
    }
    __syncthreads();

    if (amLast) {                              // last block reduces all partials
        __threadfence();                       // acquire
        __shared__ double rs[4], rc[4];
        double s = 0.0, c = 0.0;
        for (int i = tid; i < NBLK; i += TPB) {   // 4 iterations
            s += (double)partS[i];
            c += (double)partC[i];
        }
        for (int off = 32; off > 0; off >>= 1) {
            s += __shfl_down(s, off, 64);
            c += __shfl_down(c, off, 64);
        }
        if (lane == 0) { rs[wave] = s; rc[wave] = c; }
        __syncthreads();
        if (tid == 0)
            out[0] = (float)((rs[0] + rs[1] + rs[2] + rs[3]) /
                             (rc[0] + rc[1] + rc[2] + rc[3]));
    }
}

extern "C" void kernel_launch(void* const* d_in, const int* in_sizes, int n_in,
                              void* d_out, int out_size, void* d_ws, size_t ws_size,
                              hipStream_t stream) {
    const float* gt  = (const float*)d_in[0];   // [8,48,2]
    const float* sm  = (const float*)d_in[1];   // [8,48,48]
    const float* thr = (const float*)d_in[2];   // [1]

    float*        partS  = (float*)((char*)d_ws + WS_PARTS_OFF);
    unsigned int* partC  = (unsigned int*)((char*)d_ws + WS_PARTC_OFF);
    unsigned int* ticket = (unsigned int*)((char*)d_ws + WS_TICKET_OFF);

    // zero the ticket (ws is poisoned to 0xAA before every timed launch)
    hipMemsetAsync(ticket, 0, sizeof(unsigned int), stream);
    fused_kernel<<<NBLK, TPB, 0, stream>>>(gt, sm, thr, partS, partC, ticket,
                                           (float*)d_out);
}

// Round 6
// 67.545 us; speedup vs baseline: 1.2802x; 1.2802x over previous
//
#include <hip/hip_runtime.h>
#include <stdint.h>

// Problem constants (fixed by reference setup_inputs)
#define B_      8
#define N_      48
#define M_      (N_ * N_)       // 2304 candidate vectors per batch
#define CPB     128             // chunks (blocks) per batch
#define NBLK    (B_ * CPB)      // 1024 blocks = exactly 4 per CU, one round
#define TPB     256
#define PADSZ   2688            // >= max row index (2303 + 3*128) + 1; cols < 2304

// ws layout
#define WS_PARTS_OFF   0                          // float partS[NBLK]
#define WS_PARTC_OFF   (NBLK * sizeof(float))     // uint  partC[NBLK]

// R6 = R4's proven two-kernel structure + R5's proven-exact compaction.
// Burned-in lessons:
//  - NO occupancy attributes (R2/R3: allocator spills 14-46 MB to scratch).
//  - NO ticket/__threadfence single-kernel finalize (R5: 1024 device-scope
//    fences + hot-line atomics cost ~+16 us vs a second ~3 us dispatch).
//  - Compaction is exact: zero vectors produce d = +/-0 against every
//    partner -> contribute exactly 0 to sum AND count (absmax 0.0 in R5).
__global__ __launch_bounds__(TPB) void pair_kernel(
    const float* __restrict__ gt,    // [B, 48, 2]
    const float* __restrict__ sm,    // [B, 48, 48]
    const float* __restrict__ thrp,  // [1]
    float* __restrict__ partS,
    unsigned int* __restrict__ partC)
{
    __shared__ float2 cxy[PADSZ];    // compacted (vx,vy): 21504 B, 2-way aliasing = free
    __shared__ float  cw [PADSZ];    // compacted 1/norm : 10752 B
    __shared__ float  gx[N_], gy[N_];
    __shared__ float  redS[4];
    __shared__ unsigned int redC[4];
    __shared__ int blockK;

    const int tid   = threadIdx.x;
    const int lane  = tid & 63;
    const int wave  = tid >> 6;
    const int b     = blockIdx.x >> 7;        // / CPB
    const int chunk = blockIdx.x & (CPB - 1); // % CPB

    if (tid == 0) blockK = 0;
    if (tid < N_) {
        float2 g = ((const float2*)gt)[b * N_ + tid];
        gx[tid] = g.x;
        gy[tid] = g.y;
    }
    __syncthreads();

    const float thr = thrp[0];
    // Build + compact. Exact IEEE single ops match numpy's (gt_i-gt_j)*sm.
    for (int idx = tid; idx < M_; idx += TPB) {   // 9 full iterations
        float s = sm[b * M_ + idx];
        s = (s < thr) ? 0.0f : s;
        int i = idx / N_;
        int j = idx - i * N_;
        float vx = __fmul_rn(__fsub_rn(gx[i], gx[j]), s);
        float vy = __fmul_rn(__fsub_rn(gy[i], gy[j]), s);
        bool keep = (vx != 0.0f) || (vy != 0.0f);
        unsigned long long mask = __ballot(keep);
        int base = 0;
        if (lane == 0 && mask) base = atomicAdd(&blockK, __popcll(mask));
        base = __shfl(base, 0, 64);
        if (keep) {
            int off = base + __popcll(mask & ((1ull << lane) - 1ull));
            cxy[off] = make_float2(vx, vy);
            cw [off] = rsqrtf(fmaf(vx, vx, fmaf(vy, vy, 2e-9f)));
        }
    }
    __syncthreads();
    const int K = blockK;
    // zero the pad: padded rows/columns contribute exactly 0 to S and cnt
    for (int i = K + tid; i < PADSZ; i += TPB) {
        cxy[i] = make_float2(0.0f, 0.0f);
        cw[i]  = 0.0f;
    }
    __syncthreads();

    const int KP = (K + 255) >> 8;   // column sweep iterations (~5)
    float total = 0.0f;
    unsigned int cnt = 0;

    // Row passes: 4 round-robin rows at a time (live set ~25 VGPRs, no spill).
    for (int r0 = chunk; r0 < K; r0 += 4 * CPB) {
        float rx0, ry0, rx1, ry1, rx2, ry2, rx3, ry3;
        {
            float2 t0 = cxy[r0];               // wave-uniform broadcast (free)
            float2 t1 = cxy[r0 + CPB];
            float2 t2 = cxy[r0 + 2 * CPB];
            float2 t3 = cxy[r0 + 3 * CPB];     // rows >= K read zeros -> exact no-op
            rx0 = t0.x; ry0 = t0.y; rx1 = t1.x; ry1 = t1.y;
            rx2 = t2.x; ry2 = t2.y; rx3 = t3.x; ry3 = t3.y;
        }
        float a0 = 0.0f, a1 = 0.0f, a2 = 0.0f, a3 = 0.0f;
        for (int k = 0; k < KP; ++k) {
            const int n = tid + (k << 8);
            const float2 c = cxy[n];           // ds_read_b64, reused x4 rows
            const float  w = cw[n];            // ds_read_b32
            // discrete mul/mul/add (no fma contraction): exact-zero count
            // semantics identical to the fp32 numpy reference
            float d0 = __fadd_rn(__fmul_rn(rx0, c.x), __fmul_rn(ry0, c.y));
            float d1 = __fadd_rn(__fmul_rn(rx1, c.x), __fmul_rn(ry1, c.y));
            float d2 = __fadd_rn(__fmul_rn(rx2, c.x), __fmul_rn(ry2, c.y));
            float d3 = __fadd_rn(__fmul_rn(rx3, c.x), __fmul_rn(ry3, c.y));
            cnt += (d0 != 0.0f) ? 1u : 0u;
            cnt += (d1 != 0.0f) ? 1u : 0u;
            cnt += (d2 != 0.0f) ? 1u : 0u;
            cnt += (d3 != 0.0f) ? 1u : 0u;
            a0 = fmaf(fabsf(d0), w, a0);       // |d| folds into VOP3 abs modifier
            a1 = fmaf(fabsf(d1), w, a1);
            a2 = fmaf(fabsf(d2), w, a2);
            a3 = fmaf(fabsf(d3), w, a3);
        }
        total = fmaf(a0, cw[r0],           total);  // hoisted row-norm factor
        total = fmaf(a1, cw[r0 + CPB],     total);
        total = fmaf(a2, cw[r0 + 2 * CPB], total);
        total = fmaf(a3, cw[r0 + 3 * CPB], total);  // pad rows: a=0 -> exact no-op
    }

    // wave64 shuffle reduce, then cross-wave via LDS
    for (int off = 32; off > 0; off >>= 1) {
        total += __shfl_down(total, off, 64);
        cnt   += __shfl_down(cnt,   off, 64);
    }
    if (lane == 0) { redS[wave] = total; redC[wave] = cnt; }
    __syncthreads();
    if (tid == 0) {
        partS[blockIdx.x] = redS[0] + redS[1] + redS[2] + redS[3];
        partC[blockIdx.x] = redC[0] + redC[1] + redC[2] + redC[3];
    }
}

// Kernel 2: reduce the 1024 block partials (double accumulation) and divide.
// Cross-dispatch visibility via the stream dispatch boundary (R1/R4 passed
// with absmax 0.0 using exactly this structure).
__global__ __launch_bounds__(256) void finalize_kernel(
    const float* __restrict__ partS,
    const unsigned int* __restrict__ partC,
    float* __restrict__ out)
{
    __shared__ double rs[4];
    __shared__ double rc[4];
    const int tid = threadIdx.x;
    double s = 0.0, c = 0.0;
    for (int i = tid; i < NBLK; i += 256) {   // 4 iterations
        s += (double)partS[i];
        c += (double)partC[i];
    }
    for (int off = 32; off > 0; off >>= 1) {
        s += __shfl_down(s, off, 64);
        c += __shfl_down(c, off, 64);
    }
    const int wave = tid >> 6;
    if ((tid & 63) == 0) { rs[wave] = s; rc[wave] = c; }
    __syncthreads();
    if (tid == 0) {
        out[0] = (float)((rs[0] + rs[1] + rs[2] + rs[3]) /
                         (rc[0] + rc[1] + rc[2] + rc[3]));
    }
}

extern "C" void kernel_launch(void* const* d_in, const int* in_sizes, int n_in,
                              void* d_out, int out_size, void* d_ws, size_t ws_size,
                              hipStream_t stream) {
    const float* gt  = (const float*)d_in[0];   // [8,48,2]
    const float* sm  = (const float*)d_in[1];   // [8,48,48]
    const float* thr = (const float*)d_in[2];   // [1]

    float*        partS = (float*)((char*)d_ws + WS_PARTS_OFF);
    unsigned int* partC = (unsigned int*)((char*)d_ws + WS_PARTC_OFF);

    pair_kernel<<<NBLK, TPB, 0, stream>>>(gt, sm, thr, partS, partC);
    finalize_kernel<<<1, 256, 0, stream>>>(partS, partC, (float*)d_out);
}